// Round 4
// baseline (160.299 us; speedup 1.0000x reference)
//
#include <hip/hip_runtime.h>

#define NCH   256
#define NPROT 320
#define HW    16384      // 128*128
#define TAU   20.0f
#define EPSN  1e-4f

typedef _Float16 half8 __attribute__((ext_vector_type(8)));
typedef float    f32x4 __attribute__((ext_vector_type(4)));

// ---------------------------------------------------------------------------
// Kernel 1a: avg-pool sup_x (5,256,128,128) over 16x16 cells -> praw[p][c]
// (unchanged from verified baseline)
// ---------------------------------------------------------------------------
__global__ __launch_bounds__(256) void k_pool(const float* __restrict__ sup_x,
                                              float* __restrict__ praw) {
    int b = blockIdx.x;            // s*256 + c
    int t = threadIdx.x;
    const float4* plane = (const float4*)(sup_x + (size_t)b * HW);
    float rsum[8];
    #pragma unroll
    for (int r = 0; r < 8; ++r) rsum[r] = 0.f;
    #pragma unroll
    for (int i = 0; i < 16; ++i) {
        float4 v = plane[i * 256 + t];
        rsum[i >> 1] += v.x + v.y + v.z + v.w;
    }
    __shared__ float part[8][256];
    #pragma unroll
    for (int r = 0; r < 8; ++r) part[r][t] = rsum[r];
    __syncthreads();
    int R  = t >> 5;
    int cw = t & 31;
    float s = 0.f;
    #pragma unroll
    for (int a = 0; a < 8; ++a) s += part[R][a * 32 + cw];
    s += __shfl_xor(s, 1);
    s += __shfl_xor(s, 2);
    if ((t & 3) == 0) {
        int shot = b >> 8, c = b & 255;
        int p = shot * 64 + R * 8 + (cw >> 2);
        praw[(size_t)p * NCH + c] = s * (1.0f / 256.0f);
    }
}

// ---------------------------------------------------------------------------
// Kernel 1b: per-proto center + safe-normalize; emit fp16 hi/lo split in
// B-fragment layout PTh[((k>>3)*320 + p)*8 + (k&7)] (HW-verified R1/R2),
// plus sp[p] = sum_c pn[p][c] (for normalize-after-GEMM epilogue).
// ---------------------------------------------------------------------------
__device__ __forceinline__ float block_sum256(float x, float* ws4, int t) {
    #pragma unroll
    for (int o = 1; o < 64; o <<= 1) x += __shfl_xor(x, o);
    if ((t & 63) == 0) ws4[t >> 6] = x;
    __syncthreads();
    float r = ws4[0] + ws4[1] + ws4[2] + ws4[3];
    __syncthreads();
    return r;
}

__global__ __launch_bounds__(256) void k_norm(const float* __restrict__ praw,
                                              _Float16* __restrict__ PTh,
                                              _Float16* __restrict__ PTl,
                                              float* __restrict__ sp) {
    int p = blockIdx.x;
    int c = threadIdx.x;
    __shared__ float ws4[4];
    float v = praw[p * NCH + c];
    float mean = block_sum256(v, ws4, c) * (1.0f / 256.0f);
    float cen = v - mean;
    float n2 = block_sum256(cen * cen, ws4, c);
    float inv = 1.0f / fmaxf(sqrtf(n2), EPSN);
    float pn = cen * inv;
    _Float16 hi = (_Float16)pn;
    float lo = (pn - (float)hi) * 2048.0f;
    size_t idx = ((size_t)(c >> 3) * NPROT + p) * 8 + (c & 7);
    PTh[idx] = hi;
    PTl[idx] = (_Float16)lo;
    float ssum = block_sum256(pn, ws4, c);
    if (c == 0) sp[p] = ssum;
}

// ---------------------------------------------------------------------------
// Kernel 2: MFMA GEMM (32 px x 320 protos x K=256) + softmax epilogue.
// Anti-spill restructure (resubmit of R3 — container infra failure, not a
// kernel verdict):
//  - nt-OUTER loop: live accumulators = 4 f32x4 (was 20); per-nt results
//    parked in statically-indexed dva[2][5]
//  - A-tiles hold RAW q hi/lo (normalize folded into epilogue via sp/mean/invn)
//    -> fp32 qlds staging deleted; convert in-register during coalesced load;
//    LDS 70 -> 43.5 KB -> 3 blocks/CU
//  - depth-2 software prefetch on B (covers ~220cy L2 latency)
// ---------------------------------------------------------------------------
__global__ __launch_bounds__(256, 2) void k_main(const float* __restrict__ qry,
                                                 const _Float16* __restrict__ PTh,
                                                 const _Float16* __restrict__ PTl,
                                                 const float* __restrict__ sp,
                                                 float* __restrict__ out) {
    __shared__ __align__(16) _Float16 Ah[32 * 256];    // 16 KB, swizzled
    __shared__ __align__(16) _Float16 Al[32 * 256];    // 16 KB, swizzled
    __shared__ float red1[32 * 33], red2[32 * 33];     // [c0][px], pad 33
    __shared__ float meanv[32], invnv[32];
    __shared__ float Mw[4][32], Sw[4][32], Tw[4][32], Iw[4][32];
    int t = threadIdx.x;
    int pixbase = blockIdx.x * 32;

    // ---- stage: coalesced float4 read -> raw hi/lo fp16 split -> swizzled LDS
    //      (+ fused per-pixel mean/sumsq register partials) ----
    {
        int f4 = t & 7;            // which float4-of-pixels (0..7)
        int c0 = t >> 3;           // 0..31
        float ps1[4] = {0.f, 0.f, 0.f, 0.f};
        float ps2[4] = {0.f, 0.f, 0.f, 0.f};
        char* AhB = (char*)Ah;
        char* AlB = (char*)Al;
        #pragma unroll
        for (int i = 0; i < 8; ++i) {
            int c = c0 + 32 * i;
            float4 v = *(const float4*)(qry + (size_t)c * HW + pixbase + f4 * 4);
            float q[4] = {v.x, v.y, v.z, v.w};
            #pragma unroll
            for (int j = 0; j < 4; ++j) {
                int px = f4 * 4 + j;
                float x = q[j];
                _Float16 h = (_Float16)x;
                _Float16 l = (_Float16)((x - (float)h) * 2048.0f);
                int off = px * 512 + ((2 * c) ^ ((px & 7) << 4));
                *(_Float16*)(AhB + off) = h;
                *(_Float16*)(AlB + off) = l;
                ps1[j] += x;
                ps2[j] = fmaf(x, x, ps2[j]);
            }
        }
        #pragma unroll
        for (int j = 0; j < 4; ++j) {
            red1[c0 * 33 + f4 * 4 + j] = ps1[j];
            red2[c0 * 33 + f4 * 4 + j] = ps2[j];
        }
    }
    __syncthreads();
    if (t < 32) {
        float s1 = 0.f, s2 = 0.f;
        #pragma unroll
        for (int j = 0; j < 32; ++j) { s1 += red1[j * 33 + t]; s2 += red2[j * 33 + t]; }
        float mean = s1 * (1.0f / 256.0f);
        float n2 = fmaxf(s2 - s1 * mean, 0.f);   // sum (q-mean)^2
        meanv[t] = mean;
        invnv[t] = 1.0f / fmaxf(sqrtf(n2), EPSN);
    }
    __syncthreads();

    // ---- MFMA main loop: wave w owns protos [w*80, w*80+80); nt outer ----
    int lane = t & 63, w = t >> 6;
    int col = lane & 15, g4 = lane >> 4;
    int aswz = (col & 7) << 4;
    const char* AhB = (const char*)Ah + col * 512;
    const char* AlB = (const char*)Al + col * 512;
    const half8* BH = (const half8*)PTh;
    const half8* BL = (const half8*)PTl;

    f32x4 dva[2][5];
    float spv[5];

    #pragma unroll
    for (int nt = 0; nt < 5; ++nt) {
        int nb = w * 80 + nt * 16 + col;
        spv[nt] = sp[nb];
        f32x4 a1_0 = {0.f, 0.f, 0.f, 0.f}, a1_1 = {0.f, 0.f, 0.f, 0.f};
        f32x4 a2_0 = {0.f, 0.f, 0.f, 0.f}, a2_1 = {0.f, 0.f, 0.f, 0.f};
        // depth-2 prefetch pipeline on B
        half8 bh0 = BH[(0 * 4 + g4) * 320 + nb];
        half8 bl0 = BL[(0 * 4 + g4) * 320 + nb];
        half8 bh1 = BH[(1 * 4 + g4) * 320 + nb];
        half8 bl1 = BL[(1 * 4 + g4) * 320 + nb];
        #pragma unroll 2
        for (int kb = 0; kb < 8; ++kb) {
            half8 bhn{}, bln{};
            if (kb < 6) {
                bhn = BH[((kb + 2) * 4 + g4) * 320 + nb];
                bln = BL[((kb + 2) * 4 + g4) * 320 + nb];
            }
            int koff = (kb * 64 + g4 * 16) ^ aswz;
            half8 ah0 = *(const half8*)(AhB + koff);
            half8 ah1 = *(const half8*)(AhB + koff + 8192);
            half8 al0 = *(const half8*)(AlB + koff);
            half8 al1 = *(const half8*)(AlB + koff + 8192);
            a1_0 = __builtin_amdgcn_mfma_f32_16x16x32_f16(ah0, bh0, a1_0, 0, 0, 0);
            a1_1 = __builtin_amdgcn_mfma_f32_16x16x32_f16(ah1, bh0, a1_1, 0, 0, 0);
            a2_0 = __builtin_amdgcn_mfma_f32_16x16x32_f16(ah0, bl0, a2_0, 0, 0, 0);
            a2_0 = __builtin_amdgcn_mfma_f32_16x16x32_f16(al0, bh0, a2_0, 0, 0, 0);
            a2_1 = __builtin_amdgcn_mfma_f32_16x16x32_f16(ah1, bl0, a2_1, 0, 0, 0);
            a2_1 = __builtin_amdgcn_mfma_f32_16x16x32_f16(al1, bh0, a2_1, 0, 0, 0);
            bh0 = bh1; bl0 = bl1;
            bh1 = bhn; bl1 = bln;
        }
        dva[0][nt] = a1_0 + a2_0 * (1.0f / 2048.0f);
        dva[1][nt] = a1_1 + a2_1 * (1.0f / 2048.0f);
    }

    // ---- softmax partials per pixel over this wave's 80 protos ----
    #pragma unroll
    for (int mt = 0; mt < 2; ++mt) {
        #pragma unroll
        for (int r = 0; r < 4; ++r) {
            int pixel = mt * 16 + g4 * 4 + r;
            float mean = meanv[pixel], invn = invnv[pixel];
            float dv[5];
            #pragma unroll
            for (int nt = 0; nt < 5; ++nt)
                dv[nt] = TAU * invn * (dva[mt][nt][r] - mean * spv[nt]);
            float gm = dv[0];
            float gi = (float)(w * 80 + col);
            #pragma unroll
            for (int nt = 1; nt < 5; ++nt)
                if (dv[nt] > gm) { gm = dv[nt]; gi = (float)(w * 80 + nt * 16 + col); }
            // reduce (max, argmax) over the 16 fragment columns
            #pragma unroll
            for (int o = 1; o < 16; o <<= 1) {
                float om = __shfl_xor(gm, o);
                float oi = __shfl_xor(gi, o);
                if (om > gm || (om == gm && oi < gi)) { gm = om; gi = oi; }
            }
            float S = 0.f, T = 0.f;
            #pragma unroll
            for (int nt = 0; nt < 5; ++nt) {
                float e = __expf(dv[nt] - gm);
                S += e;
                T = fmaf(e, dv[nt], T);
            }
            #pragma unroll
            for (int o = 1; o < 16; o <<= 1) { S += __shfl_xor(S, o); T += __shfl_xor(T, o); }
            if (col == 0) { Mw[w][pixel] = gm; Sw[w][pixel] = S; Tw[w][pixel] = T; Iw[w][pixel] = gi; }
        }
    }
    __syncthreads();

    // ---- merge 4 waves (disjoint ascending proto ranges), write out ----
    if (t < 32) {
        float gm = Mw[0][t], gi = Iw[0][t];
        #pragma unroll
        for (int k = 1; k < 4; ++k)
            if (Mw[k][t] > gm) { gm = Mw[k][t]; gi = Iw[k][t]; }
        float S = 0.f, T = 0.f;
        #pragma unroll
        for (int k = 0; k < 4; ++k) {
            float sc = __expf(Mw[k][t] - gm);
            S = fmaf(Sw[k][t], sc, S);
            T = fmaf(Tw[k][t], sc, T);
        }
        out[pixbase + t] = T / S;           // pred_grid
        out[HW + pixbase + t] = gi;         // debug_assign
    }
}

extern "C" void kernel_launch(void* const* d_in, const int* in_sizes, int n_in,
                              void* d_out, int out_size, void* d_ws, size_t ws_size,
                              hipStream_t stream) {
    const float* qry   = (const float*)d_in[0];   // (1,1,256,128,128)
    const float* sup_x = (const float*)d_in[1];   // (1,5,1,256,128,128)
    float* out = (float*)d_out;                   // 16384 pred + 16384 assign

    float* praw   = (float*)d_ws;                        // 320*256 fp32
    _Float16* PTh = (_Float16*)(praw + NPROT * NCH);     // 320*256 fp16 (frag layout)
    _Float16* PTl = PTh + NPROT * NCH;                   // 320*256 fp16 (frag layout)
    float* sp     = (float*)(PTl + NPROT * NCH);         // 320 fp32

    k_pool<<<5 * 256, 256, 0, stream>>>(sup_x, praw);
    k_norm<<<NPROT, 256, 0, stream>>>(praw, PTh, PTl, sp);
    k_main<<<HW / 32, 256, 0, stream>>>(qry, PTh, PTl, sp, out);
}

// Round 5
// 159.423 us; speedup vs baseline: 1.0055x; 1.0055x over previous
//
#include <hip/hip_runtime.h>

#define NCH   256
#define NPROT 320
#define HW    16384      // 128*128
#define TAU   20.0f
#define EPSN  1e-4f

typedef _Float16 half8 __attribute__((ext_vector_type(8)));
typedef float    f32x4 __attribute__((ext_vector_type(4)));

// ---------------------------------------------------------------------------
// Kernel 1a: avg-pool sup_x (5,256,128,128) over 16x16 cells -> praw[p][c]
// (unchanged from verified baseline)
// ---------------------------------------------------------------------------
__global__ __launch_bounds__(256) void k_pool(const float* __restrict__ sup_x,
                                              float* __restrict__ praw) {
    int b = blockIdx.x;            // s*256 + c
    int t = threadIdx.x;
    const float4* plane = (const float4*)(sup_x + (size_t)b * HW);
    float rsum[8];
    #pragma unroll
    for (int r = 0; r < 8; ++r) rsum[r] = 0.f;
    #pragma unroll
    for (int i = 0; i < 16; ++i) {
        float4 v = plane[i * 256 + t];
        rsum[i >> 1] += v.x + v.y + v.z + v.w;
    }
    __shared__ float part[8][256];
    #pragma unroll
    for (int r = 0; r < 8; ++r) part[r][t] = rsum[r];
    __syncthreads();
    int R  = t >> 5;
    int cw = t & 31;
    float s = 0.f;
    #pragma unroll
    for (int a = 0; a < 8; ++a) s += part[R][a * 32 + cw];
    s += __shfl_xor(s, 1);
    s += __shfl_xor(s, 2);
    if ((t & 3) == 0) {
        int shot = b >> 8, c = b & 255;
        int p = shot * 64 + R * 8 + (cw >> 2);
        praw[(size_t)p * NCH + c] = s * (1.0f / 256.0f);
    }
}

// ---------------------------------------------------------------------------
// Kernel 1b: per-proto center + safe-normalize; emit fp16 hi/lo split of the
// NORMALIZED proto in B-fragment layout PTh[((k>>3)*320 + p)*8 + (k&7)]
// (HW-verified R1/R2). sp kept for layout stability (unused downstream now).
// ---------------------------------------------------------------------------
__device__ __forceinline__ float block_sum256(float x, float* ws4, int t) {
    #pragma unroll
    for (int o = 1; o < 64; o <<= 1) x += __shfl_xor(x, o);
    if ((t & 63) == 0) ws4[t >> 6] = x;
    __syncthreads();
    float r = ws4[0] + ws4[1] + ws4[2] + ws4[3];
    __syncthreads();
    return r;
}

__global__ __launch_bounds__(256) void k_norm(const float* __restrict__ praw,
                                              _Float16* __restrict__ PTh,
                                              _Float16* __restrict__ PTl,
                                              float* __restrict__ sp) {
    int p = blockIdx.x;
    int c = threadIdx.x;
    __shared__ float ws4[4];
    float v = praw[p * NCH + c];
    float mean = block_sum256(v, ws4, c) * (1.0f / 256.0f);
    float cen = v - mean;
    float n2 = block_sum256(cen * cen, ws4, c);
    float inv = 1.0f / fmaxf(sqrtf(n2), EPSN);
    float pn = cen * inv;
    _Float16 hi = (_Float16)pn;
    float lo = (pn - (float)hi) * 2048.0f;
    size_t idx = ((size_t)(c >> 3) * NPROT + p) * 8 + (c & 7);
    PTh[idx] = hi;
    PTl[idx] = (_Float16)lo;
    float ssum = block_sum256(pn, ws4, c);
    if (c == 0) sp[p] = ssum;
}

// ---------------------------------------------------------------------------
// Kernel 2: MFMA GEMM (16 px x 320 protos x K=256) + softmax epilogue.
// THIS round's single structural change: occupancy via the GRID.
//   512 blocks (32px) = 2 blocks/CU = 2 waves/SIMD (grid-limited!) was the
//   regime where 3 rounds of loop surgery were invisible. Now:
//   16 px/block x 1024 blocks = 4 blocks/CU = 4 waves/SIMD
//   (launch_bounds(256,4): VGPR<=128; steady live set ~70).
// Also: normalized-split numerics restored (R1/R2, absmax 0.0) — stage tile
// held in REGISTERS (16 floats/thread), mean/invn computed, then split;
// XCD-chunked block swizzle so neighboring pixel-tiles share an XCD L2.
// ---------------------------------------------------------------------------
__global__ __launch_bounds__(256, 4) void k_main(const float* __restrict__ qry,
                                                 const _Float16* __restrict__ PTh,
                                                 const _Float16* __restrict__ PTl,
                                                 float* __restrict__ out) {
    __shared__ __align__(16) _Float16 Ah[16 * 256];    // 8 KB, swizzled
    __shared__ __align__(16) _Float16 Al[16 * 256];    // 8 KB, swizzled
    __shared__ __align__(16) float red1[64 * 16];      // [c0][px] partial sums
    __shared__ __align__(16) float red2[64 * 16];      // [c0][px] partial sumsq
    __shared__ float meanv[16], invnv[16];
    __shared__ float Mw[4][16], Sw[4][16], Tw[4][16], Iw[4][16];
    int t = threadIdx.x;
    // XCD-chunked bijective swizzle (1024 % 8 == 0): XCD x gets tiles
    // [x*128, (x+1)*128) -> adjacent 64B qry segments stay in one L2.
    int bid = blockIdx.x;
    int tile = (bid & 7) * 128 + (bid >> 3);
    int pixbase = tile * 16;

    // ---- stage: 4 float4 loads -> 16 q-values in REGISTERS + px partials ----
    int f4 = t & 3;                // which float4-of-pixels (0..3)
    int c0 = t >> 2;               // 0..63
    float qv[4][4];                // [i][j]: channel c0+64i, pixel f4*4+j
    {
        float ps1[4] = {0.f, 0.f, 0.f, 0.f};
        float ps2[4] = {0.f, 0.f, 0.f, 0.f};
        #pragma unroll
        for (int i = 0; i < 4; ++i) {
            int c = c0 + 64 * i;
            float4 v = *(const float4*)(qry + (size_t)c * HW + pixbase + f4 * 4);
            qv[i][0] = v.x; qv[i][1] = v.y; qv[i][2] = v.z; qv[i][3] = v.w;
            ps1[0] += v.x; ps2[0] = fmaf(v.x, v.x, ps2[0]);
            ps1[1] += v.y; ps2[1] = fmaf(v.y, v.y, ps2[1]);
            ps1[2] += v.z; ps2[2] = fmaf(v.z, v.z, ps2[2]);
            ps1[3] += v.w; ps2[3] = fmaf(v.w, v.w, ps2[3]);
        }
        *(float4*)&red1[c0 * 16 + f4 * 4] = *(float4*)ps1;
        *(float4*)&red2[c0 * 16 + f4 * 4] = *(float4*)ps2;
    }
    __syncthreads();
    if (t < 16) {
        float s1 = 0.f, s2 = 0.f;
        #pragma unroll
        for (int j = 0; j < 64; ++j) { s1 += red1[j * 16 + t]; s2 += red2[j * 16 + t]; }
        float mean = s1 * (1.0f / 256.0f);
        float n2 = fmaxf(s2 - s1 * mean, 0.f);   // sum (q-mean)^2
        meanv[t] = mean;
        invnv[t] = 1.0f / fmaxf(sqrtf(n2), EPSN);
    }
    __syncthreads();

    // ---- normalize in-register, fp16 hi/lo split -> swizzled LDS A-tiles ----
    {
        char* AhB = (char*)Ah;
        char* AlB = (char*)Al;
        #pragma unroll
        for (int j = 0; j < 4; ++j) {
            int px = f4 * 4 + j;
            float mean = meanv[px], invn = invnv[px];
            #pragma unroll
            for (int i = 0; i < 4; ++i) {
                int c = c0 + 64 * i;
                float qn = (qv[i][j] - mean) * invn;
                _Float16 h = (_Float16)qn;
                _Float16 l = (_Float16)((qn - (float)h) * 2048.0f);
                int off = px * 512 + ((2 * c) ^ ((px & 7) << 4));
                *(_Float16*)(AhB + off) = h;
                *(_Float16*)(AlB + off) = l;
            }
        }
    }
    __syncthreads();

    // ---- MFMA main loop: wave w owns protos [w*80, w*80+80); nt outer ----
    int lane = t & 63, w = t >> 6;
    int col = lane & 15, g4 = lane >> 4;
    int aswz = (col & 7) << 4;
    const char* AhB = (const char*)Ah + col * 512;
    const char* AlB = (const char*)Al + col * 512;
    const half8* BH = (const half8*)PTh;
    const half8* BL = (const half8*)PTl;

    f32x4 dva[5];

    #pragma unroll
    for (int nt = 0; nt < 5; ++nt) {
        int nb = w * 80 + nt * 16 + col;
        f32x4 a1 = {0.f, 0.f, 0.f, 0.f};
        f32x4 a2 = {0.f, 0.f, 0.f, 0.f};
        #pragma unroll
        for (int kb = 0; kb < 8; ++kb) {
            half8 bh = BH[(kb * 4 + g4) * 320 + nb];
            half8 bl = BL[(kb * 4 + g4) * 320 + nb];
            int koff = (kb * 64 + g4 * 16) ^ aswz;
            half8 ah = *(const half8*)(AhB + koff);
            half8 al = *(const half8*)(AlB + koff);
            a1 = __builtin_amdgcn_mfma_f32_16x16x32_f16(ah, bh, a1, 0, 0, 0);
            a2 = __builtin_amdgcn_mfma_f32_16x16x32_f16(ah, bl, a2, 0, 0, 0);
            a2 = __builtin_amdgcn_mfma_f32_16x16x32_f16(al, bh, a2, 0, 0, 0);
        }
        dva[nt] = a1 + a2 * (1.0f / 2048.0f);
    }

    // ---- softmax partials per pixel over this wave's 80 protos ----
    #pragma unroll
    for (int r = 0; r < 4; ++r) {
        int pixel = g4 * 4 + r;          // D layout: row = (lane>>4)*4 + reg
        float dv[5];
        #pragma unroll
        for (int nt = 0; nt < 5; ++nt) dv[nt] = TAU * dva[nt][r];
        float gm = dv[0];
        float gi = (float)(w * 80 + col);
        #pragma unroll
        for (int nt = 1; nt < 5; ++nt)
            if (dv[nt] > gm) { gm = dv[nt]; gi = (float)(w * 80 + nt * 16 + col); }
        // reduce (max, argmax) over the 16 fragment columns
        #pragma unroll
        for (int o = 1; o < 16; o <<= 1) {
            float om = __shfl_xor(gm, o);
            float oi = __shfl_xor(gi, o);
            if (om > gm || (om == gm && oi < gi)) { gm = om; gi = oi; }
        }
        float S = 0.f, T = 0.f;
        #pragma unroll
        for (int nt = 0; nt < 5; ++nt) {
            float e = __expf(dv[nt] - gm);
            S += e;
            T = fmaf(e, dv[nt], T);
        }
        #pragma unroll
        for (int o = 1; o < 16; o <<= 1) { S += __shfl_xor(S, o); T += __shfl_xor(T, o); }
        if (col == 0) { Mw[w][pixel] = gm; Sw[w][pixel] = S; Tw[w][pixel] = T; Iw[w][pixel] = gi; }
    }
    __syncthreads();

    // ---- merge 4 waves (disjoint ascending proto ranges), write out ----
    if (t < 16) {
        float gm = Mw[0][t], gi = Iw[0][t];
        #pragma unroll
        for (int k = 1; k < 4; ++k)
            if (Mw[k][t] > gm) { gm = Mw[k][t]; gi = Iw[k][t]; }
        float S = 0.f, T = 0.f;
        #pragma unroll
        for (int k = 0; k < 4; ++k) {
            float sc = __expf(Mw[k][t] - gm);
            S = fmaf(Sw[k][t], sc, S);
            T = fmaf(Tw[k][t], sc, T);
        }
        out[pixbase + t] = T / S;           // pred_grid
        out[HW + pixbase + t] = gi;         // debug_assign
    }
}

extern "C" void kernel_launch(void* const* d_in, const int* in_sizes, int n_in,
                              void* d_out, int out_size, void* d_ws, size_t ws_size,
                              hipStream_t stream) {
    const float* qry   = (const float*)d_in[0];   // (1,1,256,128,128)
    const float* sup_x = (const float*)d_in[1];   // (1,5,1,256,128,128)
    float* out = (float*)d_out;                   // 16384 pred + 16384 assign

    float* praw   = (float*)d_ws;                        // 320*256 fp32
    _Float16* PTh = (_Float16*)(praw + NPROT * NCH);     // 320*256 fp16 (frag layout)
    _Float16* PTl = PTh + NPROT * NCH;                   // 320*256 fp16 (frag layout)
    float* sp     = (float*)(PTl + NPROT * NCH);         // 320 fp32

    k_pool<<<5 * 256, 256, 0, stream>>>(sup_x, praw);
    k_norm<<<NPROT, 256, 0, stream>>>(praw, PTh, PTl, sp);
    k_main<<<HW / 16, 256, 0, stream>>>(qry, PTh, PTl, out);
}